// Round 4
// baseline (312.800 us; speedup 1.0000x reference)
//
#include <hip/hip_runtime.h>
#include <hip/hip_bf16.h>

// LatentMatrixMemory: M_t = lam*M + (rho*alpha)*(k outer v); r_t = q^T M_t
// B=64, T=2048, DK=DV=128, fp32 in/out. Threshold permits bf16 compute.
//
// Round 6: 8 waves (512 thr) for 2 waves/SIMD TLP; the 1-wave/SIMD version
// was ~70% exposed-latency (13k cy/chunk vs ~3k busy).
//  - Work split per wave w = (tw = w>>1, half = w&1):
//      GEMM1 (S=q k^T):  t-rows [16tw,+16), s-cols [32*half,+32)  (2 tiles)
//      GEMM2/3 (readout): t-rows [16tw,+16), j-cols [16*half,+16) (1 tile)
//      GEMM4 (M update):  i-rows [16w,+16), all 32 j               (2 tiles)
//    No cross-wave reductions anywhere; Sd/VwT/MhT flow through LDS across
//    the existing B2 barrier.
//  - k staged chunk-ahead via global_load_lds into klds[2][64][128] fp32,
//    5-bit XOR block swizzle xk(row) = (row&7) ^ (((row>>3)&3)<<3):
//    GEMM1 b128 reads ~2-way, GEMM4 transposed scalar reads now ~2-way
//    (quads land in distinct 8-block regions) instead of 4-way.
//  - DMA issued at TOP of phase A (dest buffer dead since prev GEMM4),
//    drained by B2 -> full-phase slack. Register prefetch (q,v,lam,a,rho)
//    also issued in phase A right after current values are consumed.
//  - Two barriers/chunk (B1: prefetch regs/WAR, B2: LDS publish).
// Grid: 4 DV-splits x 64 batches = 256 blocks, XCD-chunked swizzle.

typedef float  f32x4  __attribute__((ext_vector_type(4)));
typedef short  bf16x8 __attribute__((ext_vector_type(8)));
typedef short  bf16x4 __attribute__((ext_vector_type(4)));

constexpr int B_ = 64, T_ = 2048;
constexpr int NSPLIT = 4;
constexpr int CT = 64;          // chunk length
constexpr int NCH = T_ / CT;    // 32 chunks

__device__ __forceinline__ bf16x8 cvt8(float4 a, float4 b) {
  union { __hip_bfloat162 h2[4]; bf16x8 v; } u;
  u.h2[0] = __float22bfloat162_rn(make_float2(a.x, a.y));
  u.h2[1] = __float22bfloat162_rn(make_float2(a.z, a.w));
  u.h2[2] = __float22bfloat162_rn(make_float2(b.x, b.y));
  u.h2[3] = __float22bfloat162_rn(make_float2(b.z, b.w));
  return u.v;
}

__device__ __forceinline__ float fexp2(float x) { return __builtin_exp2f(x); }
__device__ __forceinline__ float flog2(float x) { return __builtin_log2f(x); }

// physical 16B-block p of row holds logical block p ^ xk(row)
__device__ __forceinline__ int xk_of(int row) {
  return (row & 7) ^ (((row >> 3) & 3) << 3);
}

#define MFMA(a, b, c) __builtin_amdgcn_mfma_f32_16x16x32_bf16((a), (b), (c), 0, 0, 0)

__device__ __forceinline__ void gload16(const float* gsrc, float* ldst) {
  __builtin_amdgcn_global_load_lds(
      (const __attribute__((address_space(1))) void*)gsrc,
      (__attribute__((address_space(3))) void*)ldst, 16, 0, 0);
}

__global__ __launch_bounds__(512, 1) void lmm_w8(
    const float* __restrict__ q_g, const float* __restrict__ k_g,
    const float* __restrict__ v_g, const float* __restrict__ a_g,
    const float* __restrict__ r_g, const float* __restrict__ l_g,
    const float* __restrict__ m0_g, float* __restrict__ out_g)
{
  // XCD-chunked bijective swizzle: all 4 splits of a batch share an XCD.
  const int bid   = blockIdx.y * NSPLIT + blockIdx.x;
  const int b     = (bid & 7) * 8 + (bid >> 5);
  const int split = (bid >> 3) & 3;

  const int tid   = threadIdx.x;
  const int w     = tid >> 6;        // wave 0..7
  const int lane  = tid & 63;
  const int m     = lane & 15;
  const int quad  = lane >> 4;
  const int tw    = w >> 1;          // t-block for GEMM1/2/3
  const int half  = w & 1;           // s-half (GEMM1) / j-half (GEMM2/3)
  const int jbase = split * 32;

  __shared__ __align__(16) float klds[2][64][128];           // 64 KiB, swizzled
  __shared__ __align__(16) __hip_bfloat16 MhT [32][136];     // bf16(M)^T [j][i]
  __shared__ __align__(16) __hip_bfloat16 VwT [32][72];      // (ar*v)^T  [j][s]
  __shared__ __align__(16) __hip_bfloat16 VwTd[32][72];      // (ar*ratio*v)^T
  __shared__ __align__(16) __hip_bfloat16 Sd[4][16][72];     // scores [tb][t][s]

  const float* qb = q_g + (size_t)b * T_ * 128;
  const float* kb = k_g + (size_t)b * T_ * 128;
  const float* vb = v_g + (size_t)b * T_ * 128;
  const float* ab = a_g + (size_t)b * T_;
  const float* rb = r_g + (size_t)b * T_;
  const float* lb = l_g + (size_t)b * T_;
  float*       ob = out_g + (size_t)b * T_ * 128;

  // ---- M accumulator: wave w owns i-rows [16w,+16), both j 16-col tiles ----
  f32x4 M[2];
  #pragma unroll
  for (int jt = 0; jt < 2; ++jt)
    #pragma unroll
    for (int r = 0; r < 4; ++r)
      M[jt][r] = m0_g[((size_t)b * 128 + w * 16 + quad * 4 + r) * 128 +
                      jbase + jt * 16 + m];

  // ---- prefetch lane mappings ----
  const int jv   = tid & 31;   // V staging column (0..31)
  const int s8   = tid >> 5;   // V staging 4-row s-block (0..15)
  const int prow = lane >> 5;  // k-DMA: row parity within 1 KiB call
  const int pblk = lane & 31;  // k-DMA: 16B block within row

  float4 qpre[4][2];
  float  vpre[4];
  float  lpre, apre, rpre;

  // ---- chunk-0 prefetch (drained by first B1) ----
  lpre = lb[lane]; apre = ab[lane]; rpre = rb[lane];
  #pragma unroll
  for (int c = 0; c < 4; ++c) {      // wave w stages k rows [8w, 8w+8)
    const int row = w * 8 + c * 2 + prow;
    gload16(kb + (size_t)row * 128 + ((pblk ^ xk_of(row)) << 2),
            &klds[0][w * 8 + c * 2][0]);
  }
  #pragma unroll
  for (int ks = 0; ks < 4; ++ks) {
    const float* p = qb + (size_t)(tw * 16 + m) * 128 + ks * 32 + quad * 8;
    qpre[ks][0] = *(const float4*)p;
    qpre[ks][1] = *(const float4*)(p + 4);
  }
  #pragma unroll
  for (int rep = 0; rep < 4; ++rep)
    vpre[rep] = vb[(size_t)(s8 * 4 + rep) * 128 + jbase + jv];

  #pragma unroll 2
  for (int ch = 0; ch < NCH; ++ch) {
    const int t0   = ch * CT;
    const int tn   = (ch + 1 < NCH) ? t0 + CT : t0;  // clamped prefetch base
    const int buf  = ch & 1;
    const int nbuf = buf ^ 1;

    __syncthreads();  // B1: prefetched regs/klds[buf] valid; WAR on LDS bufs

    // ================= phase A =================
    // k DMA for NEXT chunk: klds[nbuf] dead since prev GEMM4 (before B1).
    // Drained at B2 -> full phase-A slack.
    #pragma unroll
    for (int c = 0; c < 4; ++c) {
      const int row = w * 8 + c * 2 + prow;
      gload16(kb + (size_t)(tn + row) * 128 + ((pblk ^ xk_of(row)) << 2),
              &klds[nbuf][w * 8 + c * 2][0]);
    }

    // decay prefix scan in log2 space (redundant per wave)
    float x = flog2(fmaxf(lpre, 1e-20f));
    #pragma unroll
    for (int d = 1; d < 64; d <<= 1) {
      const float o = __shfl_up(x, d, 64);
      if (lane >= d) x += o;
    }
    const float L2    = x;
    const float L2end = __shfl(L2, 63, 64);
    const float arp   = apre * rpre;

    bf16x8 qf[4];
    #pragma unroll
    for (int ks = 0; ks < 4; ++ks) qf[ks] = cvt8(qpre[ks][0], qpre[ks][1]);

    const int tl0 = tw * 16 + quad * 4;
    float tl[4];
    #pragma unroll
    for (int r = 0; r < 4; ++r) tl[r] = __shfl(L2, tl0 + r, 64);

    // V weights from vpre (consume before prefetch overwrite)
    float fw[4], fd[4];
    #pragma unroll
    for (int rep = 0; rep < 4; ++rep) {
      const int   s   = s8 * 4 + rep;
      const float arf = __shfl(arp, s, 64);
      const float dcf = fexp2(L2end - __shfl(L2, s, 64));   // <= 1
      fw[rep] = vpre[rep] * arf;
      fd[rep] = fw[rep] * dcf;
    }

    // next-chunk register prefetch (drained at B2; consumed next phase A)
    lpre = lb[tn + lane]; apre = ab[tn + lane]; rpre = rb[tn + lane];
    #pragma unroll
    for (int ks = 0; ks < 4; ++ks) {
      const float* p = qb + (size_t)(tn + tw * 16 + m) * 128 + ks * 32 + quad * 8;
      qpre[ks][0] = *(const float4*)p;
      qpre[ks][1] = *(const float4*)(p + 4);
    }
    #pragma unroll
    for (int rep = 0; rep < 4; ++rep)
      vpre[rep] = vb[(size_t)(tn + s8 * 4 + rep) * 128 + jbase + jv];

    // GEMM1: own 16 t-rows x own 32 s-cols, k from swizzled LDS
    f32x4 S[2] = {{0.f,0.f,0.f,0.f},{0.f,0.f,0.f,0.f}};
    #pragma unroll
    for (int sb = 0; sb < 2; ++sb) {
      const int rowk = half * 32 + sb * 16 + m;
      const int xk   = xk_of(rowk);
      #pragma unroll
      for (int ks = 0; ks < 4; ++ks) {
        const int bk0 = ks * 8 + quad * 2;
        const float4 kA = *(const float4*)&klds[buf][rowk][((bk0      ^ xk) << 2)];
        const float4 kB = *(const float4*)&klds[buf][rowk][(((bk0 + 1) ^ xk) << 2)];
        S[sb] = MFMA(qf[ks], cvt8(kA, kB), S[sb]);
      }
    }

    // decay + causal mask -> Sd (disjoint s-cols per half)
    #pragma unroll
    for (int sb = 0; sb < 2; ++sb) {
      const int   sl_i = half * 32 + sb * 16 + m;
      const float sl   = __shfl(L2, sl_i, 64);
      #pragma unroll
      for (int r = 0; r < 4; ++r) {
        const float dv = (sl_i <= tl0 + r) ? S[sb][r] * fexp2(tl[r] - sl) : 0.f;
        Sd[tw][quad * 4 + r][sl_i] = __float2bfloat16(dv);
      }
    }

    // stage VwT / VwTd (b64 per lane)
    {
      union { __hip_bfloat162 h2[2]; bf16x4 v; } uw, ud;
      uw.h2[0] = __float22bfloat162_rn(make_float2(fw[0], fw[1]));
      uw.h2[1] = __float22bfloat162_rn(make_float2(fw[2], fw[3]));
      ud.h2[0] = __float22bfloat162_rn(make_float2(fd[0], fd[1]));
      ud.h2[1] = __float22bfloat162_rn(make_float2(fd[2], fd[3]));
      *(bf16x4*)&VwT [jv][s8 * 4] = uw.v;
      *(bf16x4*)&VwTd[jv][s8 * 4] = ud.v;
    }

    // publish bf16(M)^T: wave w -> i-cols [16w,+16)
    #pragma unroll
    for (int jt = 0; jt < 2; ++jt) {
      union { __hip_bfloat162 h2[2]; uint2 u; } pk;
      pk.h2[0] = __float22bfloat162_rn(make_float2(M[jt][0], M[jt][1]));
      pk.h2[1] = __float22bfloat162_rn(make_float2(M[jt][2], M[jt][3]));
      *(uint2*)&MhT[jt * 16 + m][w * 16 + quad * 4] = pk.u;
    }

    __syncthreads();  // B2: Sd/VwT/VwTd/MhT visible; drains DMA + prefetch

    // ================= phase B =================
    // GEMM3: inter-chunk readout q . bf16(M)  (one 16x16 tile per wave)
    f32x4 R = {0.f, 0.f, 0.f, 0.f};
    #pragma unroll
    for (int ks = 0; ks < 4; ++ks) {
      const bf16x8 mb = *(const bf16x8*)&MhT[half * 16 + m][ks * 32 + quad * 8];
      R = MFMA(qf[ks], mb, R);
    }
    #pragma unroll
    for (int r = 0; r < 4; ++r) R[r] *= fexp2(tl[r]);   // P_t <= 1

    // GEMM2: intra-chunk (decay folded into Sd)
    #pragma unroll
    for (int kk = 0; kk < 2; ++kk) {
      const bf16x8 sa = *(const bf16x8*)&Sd[tw][m][kk * 32 + quad * 8];
      const bf16x8 vw = *(const bf16x8*)&VwT[half * 16 + m][kk * 32 + quad * 8];
      R = MFMA(sa, vw, R);
    }
    #pragma unroll
    for (int r = 0; r < 4; ++r)
      ob[(size_t)(t0 + tw * 16 + quad * 4 + r) * 128 + jbase + half * 16 + m] =
          R[r];

    // GEMM4: M = exp2(L2_end)*M + K^T (ar*ratio*v); transposed k reads ~2-way
    const float eend = fexp2(L2end);
    #pragma unroll
    for (int jt = 0; jt < 2; ++jt)
      #pragma unroll
      for (int r = 0; r < 4; ++r) M[jt][r] *= eend;
    #pragma unroll
    for (int kk = 0; kk < 2; ++kk) {
      float kv[8];
      #pragma unroll
      for (int u = 0; u < 8; ++u) {
        const int rows = kk * 32 + quad * 8 + u;
        const int col  = w * 16 + m;
        kv[u] = klds[buf][rows][(((col >> 2) ^ xk_of(rows)) << 2) | (col & 3)];
      }
      const bf16x8 af = cvt8(make_float4(kv[0], kv[1], kv[2], kv[3]),
                             make_float4(kv[4], kv[5], kv[6], kv[7]));
      #pragma unroll
      for (int jt = 0; jt < 2; ++jt) {
        const bf16x8 vd = *(const bf16x8*)&VwTd[jt * 16 + m][kk * 32 + quad * 8];
        M[jt] = MFMA(af, vd, M[jt]);
      }
    }
  }
}

extern "C" void kernel_launch(void* const* d_in, const int* in_sizes, int n_in,
                              void* d_out, int out_size, void* d_ws, size_t ws_size,
                              hipStream_t stream) {
  const float* q  = (const float*)d_in[0];
  const float* k  = (const float*)d_in[1];
  const float* v  = (const float*)d_in[2];
  const float* a  = (const float*)d_in[3];
  const float* r  = (const float*)d_in[4];
  const float* l  = (const float*)d_in[5];
  const float* m0 = (const float*)d_in[6];
  float* out = (float*)d_out;

  dim3 grid(NSPLIT, B_);
  lmm_w8<<<grid, 512, 0, stream>>>(q, k, v, a, r, l, m0, out);
}